// Round 6
// baseline (2739.027 us; speedup 1.0000x reference)
//
#include <hip/hip_runtime.h>
#include <cstdint>
#include <cstddef>

typedef _Float16 h16;
typedef __attribute__((ext_vector_type(8))) _Float16 half8;
typedef __attribute__((ext_vector_type(4))) _Float16 half4;
typedef __attribute__((ext_vector_type(4))) float f32x4;

#define D 1024
#define NTOK 65536
#define BM 256
#define BN 256
#define BK 64
#define NTILES (D / BK)  // 16
#define NLIN 12

// Swizzled element position for activation/weight layout:
// within each row's 128B chunk (64 fp16), 16B granules are XOR-permuted by (row&7).
__device__ __forceinline__ size_t swz_pos(int t, int o) {
  return (size_t)t * D + ((o >> 6) << 6) + ((((o >> 3) & 7) ^ (t & 7)) << 3) + (o & 7);
}

// ---------- dequant: int32 q * group scales -> fp16 W, swizzled by (o&7) ----------
__global__ __launch_bounds__(256) void k_dequant(const int* __restrict__ q,
                                                 const float* __restrict__ s,
                                                 h16* __restrict__ W) {
  const int row = blockIdx.x;        // l*1024 + o
  const int o = row & (D - 1);
  const int k0 = threadIdx.x * 4;
  const int4 qv = *(const int4*)(q + (size_t)row * D + k0);
  const float sc = s[(size_t)row * (D / 16) + (k0 >> 4)];
  half4 wv;
  wv.x = (h16)((float)qv.x * sc);
  wv.y = (h16)((float)qv.y * sc);
  wv.z = (h16)((float)qv.z * sc);
  wv.w = (h16)((float)qv.w * sc);
  const int chunk = k0 >> 6;
  const int pg = (k0 >> 3) & 7;
  const size_t idx = (size_t)row * D + (chunk << 6) + (((pg ^ (o & 7)) << 3) + (k0 & 7));
  *(half4*)(W + idx) = wv;
}

// ---------- convert: x fp32 -> fp16 swizzled by (t&7) ----------
__global__ __launch_bounds__(256) void k_convert(const float* __restrict__ x, h16* __restrict__ X) {
  const int idx = blockIdx.x * 256 + threadIdx.x;  // global 8-elem granule id
  const int t = idx >> 7, g = idx & 127;
  const int tk = ((g >> 3) << 6) + (((g & 7) ^ (t & 7)) << 3);
  const float* src = x + (size_t)t * D + tk;
  const f32x4 a = *(const f32x4*)(src);
  const f32x4 b = *(const f32x4*)(src + 4);
  half8 v;
  v[0] = (h16)a.x; v[1] = (h16)a.y; v[2] = (h16)a.z; v[3] = (h16)a.w;
  v[4] = (h16)b.x; v[5] = (h16)b.y; v[6] = (h16)b.z; v[7] = (h16)b.w;
  *(half8*)(X + (size_t)t * D + (size_t)g * 8) = v;
}

// 16 MFMA of one quadrant; QM/QN must be literals (static acc indexing, rule #20)
#define MFMA16(QM, QN)                                                          \
  {                                                                             \
    __builtin_amdgcn_s_setprio(1);                                              \
    _Pragma("unroll") for (int m = 0; m < 4; ++m) {                             \
      _Pragma("unroll") for (int n = 0; n < 2; ++n) {                           \
        acc[(QM)*4 + m][(QN)*2 + n] = __builtin_amdgcn_mfma_f32_16x16x32_f16(   \
            af[m][0], bf[n][0], acc[(QM)*4 + m][(QN)*2 + n], 0, 0, 0);          \
        acc[(QM)*4 + m][(QN)*2 + n] = __builtin_amdgcn_mfma_f32_16x16x32_f16(   \
            af[m][1], bf[n][1], acc[(QM)*4 + m][(QN)*2 + n], 0, 0, 0);          \
      }                                                                         \
    }                                                                           \
    __builtin_amdgcn_s_setprio(0);                                              \
  }

// ---------- GEMM: out[t,o] = act(sum_k A[t,k]*W[o,k] + bias[o] (+res)) ----------
// 256x256 tile, 8 waves (2M x 4N), BK=64, 2 LDS tile-slots (128KB).
// Window U (4 phases): phase 0 issues ALL of tile U+1's global_load_lds into the
// free slot; vmcnt(0) only at phase 3 (~3.5 phases of MFMA distance -> loads landed).
__global__ __launch_bounds__(512, 2) void k_gemm(const h16* __restrict__ A,
                                                 const h16* __restrict__ W,
                                                 const float* __restrict__ bias,
                                                 const h16* res, h16* out, int relu) {
  __shared__ _Float16 lds_s[65536];  // 2 slots x (A 16384 | B 16384) halfs = 128KB

  const int bid = blockIdx.x;
  const int swz = (bid & 7) * 128 + (bid >> 3);  // bijective: 1024 % 8 == 0
  const int tm = swz >> 2;                       // 0..255
  const int tn = swz & 3;                        // 0..3
  const int tid = threadIdx.x;
  const int lane = tid & 63;
  const int w = tid >> 6;   // 0..7
  const int wm = w >> 2;    // 0..1  (row half)
  const int wn = w & 3;     // 0..3  (col quarter)

  // staging source bases: per-lane GLOBAL addr carries the layout swizzle.
  // LDS dest must be WAVE-UNIFORM base; HW adds lane*16B (verified semantics, m104).
  const h16* srcA = A + (size_t)(tm * 256 + (tid >> 3)) * D + (tid & 7) * 8;
  const h16* srcB = W + (size_t)(tn * 256 + (tid >> 3)) * D + (tid & 7) * 8;

  // ds_read swizzle granule offsets (row&7 == lane&7 since all row-bases are x8)
  const int key = lane & 7;
  const int s0 = (((lane >> 4) + 0) ^ key) * 8;  // h=0
  const int s1 = (((lane >> 4) + 4) ^ key) * 8;  // h=1
  const int abase = (wm * 128 + (lane & 15)) * 64;
  const int bbase = (wn * 64 + (lane & 15)) * 64;

  f32x4 acc[8][4];
#pragma unroll
  for (int i = 0; i < 8; ++i)
#pragma unroll
    for (int j = 0; j < 4; ++j) acc[i][j] = (f32x4)0.f;

  // 8 global_load_lds per wave per tile; wave-uniform LDS base, lane offset implicit.
  // lane dest = slot*32768 + w*512 + l*4096 + lane*8  ==  linear (row_local*64 + gran*8)
  auto stage8 = [&](int slot, int T) {
    _Float16* base = lds_s + slot * 32768 + w * 512;
#pragma unroll
    for (int l = 0; l < 4; ++l)
      __builtin_amdgcn_global_load_lds(
          (const __attribute__((address_space(1))) void*)(srcA + (size_t)l * 64 * D + T * 64),
          (__attribute__((address_space(3))) void*)(base + l * 4096), 16, 0, 0);
#pragma unroll
    for (int l = 0; l < 4; ++l)
      __builtin_amdgcn_global_load_lds(
          (const __attribute__((address_space(1))) void*)(srcB + (size_t)l * 64 * D + T * 64),
          (__attribute__((address_space(3))) void*)(base + 16384 + l * 4096), 16, 0, 0);
  };

  half8 af[4][2], bf[2][2];

  auto af_load = [&](const _Float16* sA, int qmoff) {
#pragma unroll
    for (int m = 0; m < 4; ++m) {
      af[m][0] = *(const half8*)(sA + abase + qmoff + m * 1024 + s0);
      af[m][1] = *(const half8*)(sA + abase + qmoff + m * 1024 + s1);
    }
  };
  auto bf_load = [&](const _Float16* sB, int qnoff) {
#pragma unroll
    for (int n = 0; n < 2; ++n) {
      bf[n][0] = *(const half8*)(sB + bbase + qnoff + n * 1024 + s0);
      bf[n][1] = *(const half8*)(sB + bbase + qnoff + n * 1024 + s1);
    }
  };

  // prologue: tile 0
  stage8(0, 0);
  asm volatile("s_waitcnt vmcnt(0)" ::: "memory");
  __builtin_amdgcn_sched_barrier(0);
  __syncthreads();

  for (int U = 0; U < NTILES; ++U) {
    const _Float16* sA = lds_s + (U & 1) * 32768;
    const _Float16* sB = sA + 16384;
    const bool more = (U < NTILES - 1);

    // ---- phase 0: quadrant (0,0); issue next tile's 8 loads into free slot ----
    af_load(sA, 0);
    bf_load(sB, 0);
    if (more) stage8((U & 1) ^ 1, U + 1);
    __builtin_amdgcn_s_barrier();
    asm volatile("s_waitcnt lgkmcnt(0)" ::: "memory");
    __builtin_amdgcn_sched_barrier(0);
    MFMA16(0, 0);
    __builtin_amdgcn_sched_barrier(0);
    __builtin_amdgcn_s_barrier();

    // ---- phase 1: quadrant (0,1) ----
    bf_load(sB, 2048);
    __builtin_amdgcn_s_barrier();
    asm volatile("s_waitcnt lgkmcnt(0)" ::: "memory");
    __builtin_amdgcn_sched_barrier(0);
    MFMA16(0, 1);
    __builtin_amdgcn_sched_barrier(0);
    __builtin_amdgcn_s_barrier();

    // ---- phase 2: quadrant (1,0) ----
    af_load(sA, 4096);
    bf_load(sB, 0);
    __builtin_amdgcn_s_barrier();
    asm volatile("s_waitcnt lgkmcnt(0)" ::: "memory");
    __builtin_amdgcn_sched_barrier(0);
    MFMA16(1, 0);
    __builtin_amdgcn_sched_barrier(0);
    __builtin_amdgcn_s_barrier();

    // ---- phase 3: quadrant (1,1); wait next tile (issued 3 phases ago) ----
    bf_load(sB, 2048);
    __builtin_amdgcn_s_barrier();
    asm volatile("s_waitcnt lgkmcnt(0)" ::: "memory");
    __builtin_amdgcn_sched_barrier(0);
    MFMA16(1, 1);
    __builtin_amdgcn_sched_barrier(0);
    if (more) {
      asm volatile("s_waitcnt vmcnt(0)" ::: "memory");
      __builtin_amdgcn_sched_barrier(0);
    }
    __builtin_amdgcn_s_barrier();
  }

  // ---- epilogue 1: acc (+bias, +relu) -> LDS 256x256 output-swizzled ----
  // C/D map: col(o)=lane&15, row(t)=(lane>>4)*4+j; local key tl&7 == global (tm*256+tl)&7
  _Float16* ldc = lds_s;
#pragma unroll
  for (int nf = 0; nf < 4; ++nf) {
    const int ol = wn * 64 + nf * 16 + (lane & 15);
    const float bv = bias[tn * 256 + ol];
#pragma unroll
    for (int mf = 0; mf < 8; ++mf) {
      const int tl0 = wm * 128 + mf * 16 + ((lane >> 4) << 2);
#pragma unroll
      for (int j = 0; j < 4; ++j) {
        const int tl = tl0 + j;
        float v = acc[mf][nf][j] + bv;
        if (relu) v = fmaxf(v, 0.f);
        ldc[tl * 256 + ((ol >> 6) << 6) + ((((ol >> 3) & 7) ^ (tl & 7)) << 3) + (ol & 7)] = (h16)v;
      }
    }
  }
  __syncthreads();

  // ---- epilogue 2: coalesced half8 read-back (+res), full-line global stores ----
#pragma unroll
  for (int p = 0; p < 16; ++p) {
    const int g = p * 512 + tid;
    const int tl = g >> 5, c = g & 31;
    half8 v = *(const half8*)(ldc + tl * 256 + c * 8);
    const size_t gpos = (size_t)(tm * 256 + tl) * D + tn * 256 + c * 8;
    if (res) {
      const half8 r = *(const half8*)(res + gpos);
#pragma unroll
      for (int j = 0; j < 8; ++j) v[j] = (h16)((float)v[j] + (float)r[j]);
    }
    *(half8*)(out + gpos) = v;
  }
}

// ---------- LayerNorm, wave per row (1024 elems = 16/lane) ----------
__device__ __forceinline__ void ln_stats(const half8& v0, const half8& v1, float& mu, float& rs) {
  float sum = 0.f, ss = 0.f;
#pragma unroll
  for (int j = 0; j < 8; ++j) {
    float f0 = (float)v0[j], f1 = (float)v1[j];
    sum += f0 + f1;
    ss += f0 * f0 + f1 * f1;
  }
#pragma unroll
  for (int m = 32; m > 0; m >>= 1) {
    sum += __shfl_xor(sum, m);
    ss += __shfl_xor(ss, m);
  }
  mu = sum * (1.f / D);
  const float var = ss * (1.f / D) - mu * mu;
  rs = rsqrtf(var + 1e-5f);
}

__global__ __launch_bounds__(256) void k_ln_mid(h16* h, const float* __restrict__ w, const float* __restrict__ b) {
  const int t = blockIdx.x * 4 + (threadIdx.x >> 6);
  const int lane = threadIdx.x & 63;
  h16* row = h + (size_t)t * D;
  half8 v0 = *(const half8*)(row + (size_t)lane * 8);
  half8 v1 = *(const half8*)(row + (size_t)(lane + 64) * 8);
  float mu, rs;
  ln_stats(v0, v1, mu, rs);
  const int tk0 = ((lane >> 3) << 6) + (((lane & 7) ^ (t & 7)) << 3);
  const int g1 = lane + 64;
  const int tk1 = ((g1 >> 3) << 6) + (((g1 & 7) ^ (t & 7)) << 3);
#pragma unroll
  for (int j = 0; j < 8; ++j) {
    v0[j] = (h16)(((float)v0[j] - mu) * rs * w[tk0 + j] + b[tk0 + j]);
    v1[j] = (h16)(((float)v1[j] - mu) * rs * w[tk1 + j] + b[tk1 + j]);
  }
  *(half8*)(row + (size_t)lane * 8) = v0;
  *(half8*)(row + (size_t)(lane + 64) * 8) = v1;
}

__global__ __launch_bounds__(256) void k_ln_final(const h16* __restrict__ h, const float* __restrict__ w,
                                                  const float* __restrict__ b, float* __restrict__ out) {
  const int t = blockIdx.x * 4 + (threadIdx.x >> 6);
  const int lane = threadIdx.x & 63;
  const h16* row = h + (size_t)t * D;
  half8 v0 = *(const half8*)(row + (size_t)lane * 8);
  half8 v1 = *(const half8*)(row + (size_t)(lane + 64) * 8);
  float mu, rs;
  ln_stats(v0, v1, mu, rs);
  const int tk0 = ((lane >> 3) << 6) + (((lane & 7) ^ (t & 7)) << 3);
  const int g1 = lane + 64;
  const int tk1 = ((g1 >> 3) << 6) + (((g1 & 7) ^ (t & 7)) << 3);
  float* orow = out + (size_t)t * D;
#pragma unroll
  for (int j = 0; j < 8; ++j) {
    orow[tk0 + j] = ((float)v0[j] - mu) * rs * w[tk0 + j] + b[tk0 + j];
    orow[tk1 + j] = ((float)v1[j] - mu) * rs * w[tk1 + j] + b[tk1 + j];
  }
}

extern "C" void kernel_launch(void* const* d_in, const int* in_sizes, int n_in,
                              void* d_out, int out_size, void* d_ws, size_t ws_size,
                              hipStream_t stream) {
  const float* x = (const float*)d_in[0];
  const int* qw = (const int*)d_in[1];
  const float* scales = (const float*)d_in[2];
  const float* bias = (const float*)d_in[3];
  const float* lnw = (const float*)d_in[4];
  const float* lnb = (const float*)d_in[5];
  float* out = (float*)d_out;

  // Exact scratch need: X (65536x1024 fp16 = 128MB) + W (12x1024x1024 fp16 = 24MB)
  if (ws_size < (size_t)152 * 1024 * 1024) return;

  char* ws = (char*)d_ws;
  h16* X = (h16*)ws;                                    // 128MB activation + residual
  h16* W = (h16*)(ws + (size_t)128 * 1024 * 1024);      // 12 x 2MB fp16, swizzled
  h16* Y = (h16*)d_out;                                 // scratch in d_out (dead before final LN)
  h16* Z = Y + (size_t)64 * 1024 * 1024;                // second half of d_out

  k_dequant<<<NLIN * D, 256, 0, stream>>>(qw, scales, W);
  k_convert<<<(NTOK * (D / 8)) / 256, 256, 0, stream>>>(x, X);

  const int GG = (NTOK / BM) * (D / BN);  // 256 * 4 = 1024
  for (int blk = 0; blk < 4; ++blk) {
    const int l0 = 3 * blk;
    k_gemm<<<GG, 512, 0, stream>>>(X, W + (size_t)(l0 + 0) * D * D, bias + (l0 + 0) * D, nullptr, Y, 1);
    k_gemm<<<GG, 512, 0, stream>>>(Y, W + (size_t)(l0 + 1) * D * D, bias + (l0 + 1) * D, nullptr, Z, 1);
    k_gemm<<<GG, 512, 0, stream>>>(Z, W + (size_t)(l0 + 2) * D * D, bias + (l0 + 2) * D, X, X, 0);
    if (blk < 3)
      k_ln_mid<<<NTOK / 4, 256, 0, stream>>>(X, lnw + blk * D, lnb + blk * D);
    else
      k_ln_final<<<NTOK / 4, 256, 0, stream>>>(X, lnw + blk * D, lnb + blk * D, out);
  }
}